// Round 9
// baseline (1276.544 us; speedup 1.0000x reference)
//
#include <hip/hip_runtime.h>

// LAYER_IDX = [0, 4096, 6144, 7168, 7680, 7682]
// layer1: 4096->2048 ebase 0       | layer2: 2048->1024 ebase 262144
// layer3: 1024->512  ebase 393216  | out: 512->2        ebase 458752
#define BATCH 512
#define FAN_IN 128
#define EPS 1e-5f
#define NB 1024   // 4 blocks/CU x 256 CUs -- all co-resident (16KB LDS, VGPR<=128)

typedef unsigned short u16;
typedef unsigned int u32;
typedef __attribute__((ext_vector_type(8))) short short8;   // 8 bf16
typedef __attribute__((ext_vector_type(4))) float f32x4;

__device__ __forceinline__ u16 f2bf(float f) {   // fp32->bf16 RNE
    union { float f; u32 u; } v; v.f = f;
    u32 r = v.u + 0x7fffu + ((v.u >> 16) & 1u);
    return (u16)(r >> 16);
}
__device__ __forceinline__ float bf2f(u16 h) {
    union { u32 u; float f; } v; v.u = ((u32)h) << 16; return v.f;
}
__device__ __forceinline__ void ld16(const void* g, void* l) {  // async global->LDS 16B
    __builtin_amdgcn_global_load_lds(
        (const __attribute__((address_space(1))) u32*)g,
        (__attribute__((address_space(3))) u32*)l, 16, 0, 0);
}

// ---------------------------------------------------------------------------
// Grid-wide flag-array barrier (no RMW serialization).
// Arrival: block i RELEASE-stores flags[i]=target (parallel, distinct addrs).
// Block 0 ACQUIRE-polls all flags, then RELEASE-publishes gen=target.
// Others ACQUIRE-spin on gen. Transitive release/acquire chain at agent
// scope => all pre-barrier stores visible across XCDs. Bounded spins.
__device__ __forceinline__ void gsync(u32* flags, u32* gen, u32 target) {
    __syncthreads();
    const int t = threadIdx.x;
    if (blockIdx.x == 0) {
        for (int i = 1 + t; i < NB; i += 256) {
            for (long it = 0; it < 400000; ++it) {
                if (__hip_atomic_load(&flags[i], __ATOMIC_ACQUIRE,
                                      __HIP_MEMORY_SCOPE_AGENT) >= target) break;
                __builtin_amdgcn_s_sleep(1);
            }
        }
        __syncthreads();
        if (t == 0)
            __hip_atomic_store(gen, target, __ATOMIC_RELEASE,
                               __HIP_MEMORY_SCOPE_AGENT);
    } else {
        if (t == 0) {
            __hip_atomic_store(&flags[blockIdx.x], target, __ATOMIC_RELEASE,
                               __HIP_MEMORY_SCOPE_AGENT);
            for (long it = 0; it < 400000; ++it) {
                if (__hip_atomic_load(gen, __ATOMIC_ACQUIRE,
                                      __HIP_MEMORY_SCOPE_AGENT) >= target) break;
                __builtin_amdgcn_s_sleep(1);
            }
        }
    }
    __syncthreads();
}

// ---------------------------------------------------------------------------
// Partial GEMM tile: Cz[z][M x 512] = A * Bb^T over K-chunk z. 64x64 tile,
// BK=32, dbuf LDS (global_load_lds), XOR swizzle. Plain stores.
__device__ __forceinline__ void gemm_stage(
    u16* SM, int unit, int mshift, const u16* __restrict__ A,
    const u16* __restrict__ Bb, float* __restrict__ Cz,
    int M, int K, int kchunk) {
    u16* sA = SM;          // 2 bufs x 2048 u16
    u16* sB = SM + 4096;
    const int tid = threadIdx.x;
    const int m_t = unit & ((1 << mshift) - 1);
    const int rest = unit >> mshift;
    const int n_t = rest & 7;
    const int z = rest >> 3;
    const int m0 = m_t * 64, n0 = n_t * 64, kbase = z * kchunk;
    float* Cp = Cz + (size_t)z * M * BATCH;

    const int r = tid >> 2, c = tid & 3;
    const int q = c ^ ((r ^ (r >> 2)) & 3);
    const u16* gA = A + (size_t)(m0 + r) * K + kbase + q * 8;
    const u16* gB = Bb + (size_t)(n0 + r) * K + kbase + q * 8;
    const int lo = tid * 8;

    const int wave = tid >> 6, lane = tid & 63;
    const int l15 = lane & 15, quad = lane >> 4;
    const int moff = (wave & 1) * 32, noff = (wave >> 1) * 32;
    int offA[2], offB[2];
#pragma unroll
    for (int i = 0; i < 2; ++i) {
        const int ra = moff + i * 16 + l15;
        offA[i] = ra * 32 + ((quad ^ ((ra ^ (ra >> 2)) & 3)) * 8);
        const int rb = noff + i * 16 + l15;
        offB[i] = rb * 32 + ((quad ^ ((rb ^ (rb >> 2)) & 3)) * 8);
    }

    f32x4 acc[2][2] = {};
    const int niter = kchunk >> 5;
    ld16(gA, &sA[lo]); ld16(gB, &sB[lo]);
    for (int it = 0; it < niter; ++it) {
        __syncthreads();
        if (it + 1 < niter) {
            const int k0 = (it + 1) << 5;
            const int nb = ((it + 1) & 1) * 2048;
            ld16(gA + k0, &sA[nb + lo]); ld16(gB + k0, &sB[nb + lo]);
        }
        const u16* a = sA + (it & 1) * 2048;
        const u16* b = sB + (it & 1) * 2048;
        const short8 a0 = *(const short8*)(a + offA[0]);
        const short8 a1 = *(const short8*)(a + offA[1]);
        const short8 b0 = *(const short8*)(b + offB[0]);
        const short8 b1 = *(const short8*)(b + offB[1]);
        acc[0][0] = __builtin_amdgcn_mfma_f32_16x16x32_bf16(a0, b0, acc[0][0], 0, 0, 0);
        acc[0][1] = __builtin_amdgcn_mfma_f32_16x16x32_bf16(a0, b1, acc[0][1], 0, 0, 0);
        acc[1][0] = __builtin_amdgcn_mfma_f32_16x16x32_bf16(a1, b0, acc[1][0], 0, 0, 0);
        acc[1][1] = __builtin_amdgcn_mfma_f32_16x16x32_bf16(a1, b1, acc[1][1], 0, 0, 0);
    }
#pragma unroll
    for (int i = 0; i < 2; ++i) {
        const int mg = m0 + moff + i * 16 + quad * 4;
#pragma unroll
        for (int rr = 0; rr < 4; ++rr)
#pragma unroll
            for (int j = 0; j < 2; ++j) {
                const int ng = n0 + noff + j * 16 + l15;
                Cp[(size_t)(mg + rr) * BATCH + ng] = acc[i][j][rr];
            }
    }
}

// ---------------------------------------------------------------------------
// Sum Z K-partials + bias -> fp32 C; per-column stat atomics. unit = 8 rows.
__device__ __forceinline__ void reduce_stage(
    int u, const float* __restrict__ Cz, float* __restrict__ C,
    const float* __restrict__ bias_l, float* __restrict__ st, int M, int Z) {
    const int t = threadIdx.x;
    const int m0 = u * 8;
    const size_t zs = (size_t)M * BATCH;
    float s0 = 0.f, q0 = 0.f, s1 = 0.f, q1 = 0.f;
#pragma unroll 2
    for (int m = 0; m < 8; ++m) {
        const size_t off = (size_t)(m0 + m) * BATCH + t * 2;
        float vx = 0.f, vy = 0.f;
        for (int zz = 0; zz < Z; ++zz) {
            const float2 v = *(const float2*)(Cz + (size_t)zz * zs + off);
            vx += v.x; vy += v.y;
        }
        const float bv = bias_l[m0 + m];
        vx += bv; vy += bv;
        float2 o; o.x = vx; o.y = vy;
        *(float2*)(C + off) = o;
        s0 += vx; q0 += vx * vx;
        s1 += vy; q1 += vy * vy;
    }
    atomicAdd(&st[t * 2], s0);
    atomicAdd(&st[t * 2 + 1], s1);
    atomicAdd(&st[BATCH + t * 2], q0);
    atomicAdd(&st[BATCH + t * 2 + 1], q1);
}

// ---------------------------------------------------------------------------
// LN+ReLU apply + transpose: C fp32 [M][512] -> actb bf16 [512][M].
__device__ __forceinline__ void ln_stage(
    u16* SM, int unit, const float* __restrict__ act,
    const float* __restrict__ st, const float* __restrict__ gamma_l,
    const float* __restrict__ beta_l, u16* __restrict__ actb,
    int M, float invDim) {
    u16 (*tile)[40] = (u16(*)[40])SM;
    const int t = threadIdx.x;
    const int m0 = (unit >> 4) * 32, n0 = (unit & 15) * 32;
    {
        const int m = t >> 3, nq = t & 7;
        const float4 v = *(const float4*)(act + (size_t)(m0 + m) * BATCH + n0 + nq * 4);
        const float g = gamma_l[m0 + m], bt = beta_l[m0 + m];
        const float4 s1 = *(const float4*)(st + n0 + nq * 4);
        const float4 s2 = *(const float4*)(st + BATCH + n0 + nq * 4);
        float mn[4], rs[4];
        mn[0] = s1.x * invDim; mn[1] = s1.y * invDim; mn[2] = s1.z * invDim; mn[3] = s1.w * invDim;
        rs[0] = rsqrtf(s2.x * invDim - mn[0] * mn[0] + EPS);
        rs[1] = rsqrtf(s2.y * invDim - mn[1] * mn[1] + EPS);
        rs[2] = rsqrtf(s2.z * invDim - mn[2] * mn[2] + EPS);
        rs[3] = rsqrtf(s2.w * invDim - mn[3] * mn[3] + EPS);
        const float vv[4] = {v.x, v.y, v.z, v.w};
#pragma unroll
        for (int i = 0; i < 4; ++i)
            tile[nq * 4 + i][m] = f2bf(fmaxf(fmaf(g * (vv[i] - mn[i]), rs[i], bt), 0.0f));
    }
    __syncthreads();
    {
        const int n = t >> 3, mq = t & 7;
        u16 o[4];
#pragma unroll
        for (int i = 0; i < 4; ++i) o[i] = tile[n][mq * 4 + i];
        *(uint2*)(actb + (size_t)(n0 + n) * M + m0 + mq * 4) = *(const uint2*)o;
    }
}

// ---------------------------------------------------------------------------
// init: zero barrier state (gen + NB flags) + stats.
__global__ __launch_bounds__(256) void init(u32* __restrict__ bar,
                                            float* __restrict__ stats) {
    const int t = threadIdx.x;
    for (int i = t; i < NB + 1; i += 256) bar[i] = 0u;
    for (int i = t; i < 3072; i += 256) stats[i] = 0.f;
}

// ---------------------------------------------------------------------------
__global__ __launch_bounds__(256, 4) void mega(
    const float* __restrict__ x, const float* __restrict__ weight,
    const float* __restrict__ bias, const float* __restrict__ ln_gamma,
    const float* __restrict__ ln_beta, const int* __restrict__ edge_src,
    float* __restrict__ out, void* __restrict__ ws) {
    __shared__ uint4 smraw[1024];   // 16 KB, all stages alias this
    u16* SM = (u16*)smraw;

    // ws layout
    float* Cz1   = (float*)ws;                         // 4 x [2048x512]
    float* Cz2   = Cz1 + (size_t)4 * 2048 * 512;       // 8 x [1024x512]
    float* Cz3   = Cz2 + (size_t)8 * 1024 * 512;       // 8 x [512x512]
    float* C1    = Cz3 + (size_t)8 * 512 * 512;
    float* C2    = C1 + (size_t)2048 * 512;
    float* C3    = C2 + (size_t)1024 * 512;
    float* stats = C3 + (size_t)512 * 512;             // 3 x 1024
    u16*   xb    = (u16*)(stats + 3072);               // [512x4096]
    u16*   actb1 = xb + (size_t)512 * 4096;            // [512x2048]
    u16*   actb2 = actb1 + (size_t)512 * 2048;         // [512x1024]
    u16*   actb3 = actb2 + (size_t)512 * 1024;         // [512x512]
    u16*   Wd    = actb3 + (size_t)512 * 512;          // 11534336 bf16
    u32*   bar   = (u32*)(Wd + 11534336);              // gen, flags[NB]
    float* st1 = stats, *st2 = stats + 1024, *st3 = stats + 2048;
    u32* gen = bar, *flags = bar + 1;

    const int bid = blockIdx.x, t = threadIdx.x;

    // ---- stage 0: prep (densify W, x->bf16)
    for (int u = bid; u < 4096; u += NB) {
        __syncthreads();   // LDS reuse guard between loop iterations
        if (u < 3584) {
            float* row = (float*)SM;
            int Kin, ebase, srcbase; u16* outrow;
            if (u < 2048)      { Kin = 4096; ebase = u * 128;                 srcbase = 0;    outrow = Wd + (size_t)u * 4096; }
            else if (u < 3072) { int q2 = u - 2048; Kin = 2048; ebase = 262144 + q2 * 128; srcbase = 4096; outrow = Wd + 8388608  + (size_t)q2 * 2048; }
            else               { int q2 = u - 3072; Kin = 1024; ebase = 393216 + q2 * 128; srcbase = 6144; outrow = Wd + 10485760 + (size_t)q2 * 1024; }
            for (int k = t; k < Kin; k += 256) row[k] = 0.f;
            __syncthreads();
            if (t < FAN_IN)
                atomicAdd(&row[edge_src[ebase + t] - srcbase], weight[ebase + t]);
            __syncthreads();
            for (int k0 = t * 8; k0 < Kin; k0 += 2048) {
                u16 pk[8];
#pragma unroll
                for (int i = 0; i < 8; ++i) pk[i] = f2bf(row[k0 + i]);
                *(uint4*)(outrow + k0) = *(const uint4*)pk;
            }
        } else {
            const int b = u - 3584;
            const float* xr = x + (size_t)b * 4096;
            u16* xo = xb + (size_t)b * 4096;
            for (int k0 = t * 8; k0 < 4096; k0 += 2048) {
                const float4 f0 = *(const float4*)(xr + k0);
                const float4 f1 = *(const float4*)(xr + k0 + 4);
                uint4 pk;
                pk.x = f2bf(f0.x) | ((u32)f2bf(f0.y) << 16);
                pk.y = f2bf(f0.z) | ((u32)f2bf(f0.w) << 16);
                pk.z = f2bf(f1.x) | ((u32)f2bf(f1.y) << 16);
                pk.w = f2bf(f1.z) | ((u32)f2bf(f1.w) << 16);
                *(uint4*)(xo + k0) = pk;
            }
        }
    }
    gsync(flags, gen, 1);

    // ---- layer 1: G1 (1024 units: 32m x 8n x 4z, kchunk 1024)
    gemm_stage(SM, bid, 5, Wd, xb, Cz1, 2048, 4096, 1024);
    gsync(flags, gen, 2);
    if (bid < 256) reduce_stage(bid, Cz1, C1, bias, st1, 2048, 4);
    gsync(flags, gen, 3);
    ln_stage(SM, bid, C1, st1, ln_gamma, ln_beta, actb1, 2048, 1.0f / 2048.0f);
    gsync(flags, gen, 4);

    // ---- layer 2: G2 (1024 units: 16m x 8n x 8z, kchunk 256)
    gemm_stage(SM, bid, 4, Wd + 8388608, actb1, Cz2, 1024, 2048, 256);
    gsync(flags, gen, 5);
    if (bid < 128) reduce_stage(bid, Cz2, C2, bias + 2048, st2, 1024, 8);
    gsync(flags, gen, 6);
    if (bid < 512) ln_stage(SM, bid, C2, st2, ln_gamma + 2048, ln_beta + 2048,
                            actb2, 1024, 1.0f / 1024.0f);
    gsync(flags, gen, 7);

    // ---- layer 3: G3 (512 units: 8m x 8n x 8z, kchunk 128)
    if (bid < 512) gemm_stage(SM, bid, 3, Wd + 10485760, actb2, Cz3, 512, 1024, 128);
    gsync(flags, gen, 8);
    if (bid < 64) reduce_stage(bid, Cz3, C3, bias + 3072, st3, 512, 8);
    gsync(flags, gen, 9);
    if (bid < 256) ln_stage(SM, bid, C3, st3, ln_gamma + 3072, ln_beta + 3072,
                            actb3, 512, 1.0f / 512.0f);
    gsync(flags, gen, 10);

    // ---- output layer: 4 units x 256 outputs
    if (bid < 4) {
        float* w_s = (float*)SM;
        int*   s_s = (int*)(w_s + 256);
        w_s[t] = weight[458752 + t];
        s_s[t] = edge_src[458752 + t] - 7168;
        __syncthreads();
        const int g = bid * 256 + t;        // 0..1023
        const int b = g >> 1, j = g & 1;
        const u16* rowp = actb3 + (size_t)b * 512;
        const int kb = j * FAN_IN;
        float acc = 0.f;
#pragma unroll 8
        for (int k = 0; k < FAN_IN; ++k)
            acc += w_s[kb + k] * bf2f(rowp[s_s[kb + k]]);
        out[(size_t)b * 2 + j] = acc + bias[3584 + j];
    }
}

// ---------------------------------------------------------------------------
extern "C" void kernel_launch(void* const* d_in, const int* in_sizes, int n_in,
                              void* d_out, int out_size, void* d_ws, size_t ws_size,
                              hipStream_t stream) {
    const float* x        = (const float*)d_in[0];
    const float* weight   = (const float*)d_in[1];
    const float* bias     = (const float*)d_in[2];
    const float* ln_gamma = (const float*)d_in[3];
    const float* ln_beta  = (const float*)d_in[4];
    const int*   edge_src = (const int*)d_in[5];
    float* out = (float*)d_out;

    // barrier + stats pointers (same arithmetic as in mega)
    float* Czall = (float*)d_ws;
    float* stats = Czall + (size_t)4 * 2048 * 512 + (size_t)8 * 1024 * 512 +
                   (size_t)8 * 512 * 512 + (size_t)2048 * 512 +
                   (size_t)1024 * 512 + (size_t)512 * 512;
    u16* Wd = (u16*)(stats + 3072) + (size_t)512 * 4096 + (size_t)512 * 2048 +
              (size_t)512 * 1024 + (size_t)512 * 512;
    u32* bar = (u32*)(Wd + 11534336);

    init<<<1, 256, 0, stream>>>(bar, stats);
    mega<<<NB, 256, 0, stream>>>(x, weight, bias, ln_gamma, ln_beta,
                                 edge_src, out, d_ws);
}

// Round 10
// 435.136 us; speedup vs baseline: 2.9337x; 2.9337x over previous
//
#include <hip/hip_runtime.h>

// LAYER_IDX = [0, 4096, 6144, 7168, 7680, 7682]
// layer1: 4096->2048 ebase 0       | layer2: 2048->1024 ebase 262144
// layer3: 1024->512  ebase 393216  | out: 512->2        ebase 458752
#define BATCH 512
#define FAN_IN 128
#define EPS 1e-5f
#define NB 1024   // 4 blocks/CU x 256 CUs -- all co-resident (16KB LDS, VGPR<=128)

typedef unsigned short u16;
typedef unsigned int u32;
typedef __attribute__((ext_vector_type(8))) short short8;   // 8 bf16
typedef __attribute__((ext_vector_type(4))) float f32x4;

__device__ __forceinline__ u16 f2bf(float f) {   // fp32->bf16 RNE
    union { float f; u32 u; } v; v.f = f;
    u32 r = v.u + 0x7fffu + ((v.u >> 16) & 1u);
    return (u16)(r >> 16);
}
__device__ __forceinline__ float bf2f(u16 h) {
    union { u32 u; float f; } v; v.u = ((u32)h) << 16; return v.f;
}
__device__ __forceinline__ void ld16(const void* g, void* l) {  // async global->LDS 16B
    __builtin_amdgcn_global_load_lds(
        (const __attribute__((address_space(1))) u32*)g,
        (__attribute__((address_space(3))) u32*)l, 16, 0, 0);
}

// ---------------------------------------------------------------------------
// Grid barrier with RELAXED spins (no acquire-per-poll L2-invalidate storm).
// Arrive: release FENCE once (L2 writeback) + relaxed flag store.
// Spin: relaxed loads only (LLC-served, no cache invalidation).
// Exit: acquire fence once. Block 0: relaxed-poll flags, acq_rel fence,
// relaxed gen publish. Transitive release->acquire chain across XCDs (G16).
__device__ __forceinline__ void gsync(u32* flags, u32* gen, u32 target) {
    __syncthreads();   // drains this block's vmem stores to L2
    const int t = threadIdx.x;
    if (blockIdx.x == 0) {
        for (int i = 1 + t; i < NB; i += 256)
            for (long it = 0; it < 2000000; ++it) {
                if (__hip_atomic_load(&flags[i], __ATOMIC_RELAXED,
                                      __HIP_MEMORY_SCOPE_AGENT) >= target) break;
                __builtin_amdgcn_s_sleep(8);
            }
        __syncthreads();
        if (t == 0) {
            __builtin_amdgcn_fence(__ATOMIC_ACQ_REL, "agent");
            __hip_atomic_store(gen, target, __ATOMIC_RELAXED,
                               __HIP_MEMORY_SCOPE_AGENT);
        }
    } else if (t == 0) {
        __builtin_amdgcn_fence(__ATOMIC_RELEASE, "agent");
        __hip_atomic_store(&flags[blockIdx.x], target, __ATOMIC_RELAXED,
                           __HIP_MEMORY_SCOPE_AGENT);
        for (long it = 0; it < 2000000; ++it) {
            if (__hip_atomic_load(gen, __ATOMIC_RELAXED,
                                  __HIP_MEMORY_SCOPE_AGENT) >= target) break;
            __builtin_amdgcn_s_sleep(8);
        }
        __builtin_amdgcn_fence(__ATOMIC_ACQUIRE, "agent");
    }
    __syncthreads();
}

// ---------------------------------------------------------------------------
// Partial GEMM tile: Cz[z][M x 512] = A * Bb^T over K-chunk z. 64x64 tile,
// BK=32, dbuf LDS (global_load_lds), XOR swizzle. Plain stores.
__device__ __forceinline__ void gemm_stage(
    u16* SM, int unit, int mshift, const u16* __restrict__ A,
    const u16* __restrict__ Bb, float* __restrict__ Cz,
    int M, int K, int kchunk) {
    u16* sA = SM;          // 2 bufs x 2048 u16
    u16* sB = SM + 4096;
    const int tid = threadIdx.x;
    const int m_t = unit & ((1 << mshift) - 1);
    const int rest = unit >> mshift;
    const int n_t = rest & 7;
    const int z = rest >> 3;
    const int m0 = m_t * 64, n0 = n_t * 64, kbase = z * kchunk;
    float* Cp = Cz + (size_t)z * M * BATCH;

    const int r = tid >> 2, c = tid & 3;
    const int q = c ^ ((r ^ (r >> 2)) & 3);
    const u16* gA = A + (size_t)(m0 + r) * K + kbase + q * 8;
    const u16* gB = Bb + (size_t)(n0 + r) * K + kbase + q * 8;
    const int lo = tid * 8;

    const int wave = tid >> 6, lane = tid & 63;
    const int l15 = lane & 15, quad = lane >> 4;
    const int moff = (wave & 1) * 32, noff = (wave >> 1) * 32;
    int offA[2], offB[2];
#pragma unroll
    for (int i = 0; i < 2; ++i) {
        const int ra = moff + i * 16 + l15;
        offA[i] = ra * 32 + ((quad ^ ((ra ^ (ra >> 2)) & 3)) * 8);
        const int rb = noff + i * 16 + l15;
        offB[i] = rb * 32 + ((quad ^ ((rb ^ (rb >> 2)) & 3)) * 8);
    }

    f32x4 acc[2][2] = {};
    const int niter = kchunk >> 5;
    ld16(gA, &sA[lo]); ld16(gB, &sB[lo]);
    for (int it = 0; it < niter; ++it) {
        __syncthreads();
        if (it + 1 < niter) {
            const int k0 = (it + 1) << 5;
            const int nb = ((it + 1) & 1) * 2048;
            ld16(gA + k0, &sA[nb + lo]); ld16(gB + k0, &sB[nb + lo]);
        }
        const u16* a = sA + (it & 1) * 2048;
        const u16* b = sB + (it & 1) * 2048;
        const short8 a0 = *(const short8*)(a + offA[0]);
        const short8 a1 = *(const short8*)(a + offA[1]);
        const short8 b0 = *(const short8*)(b + offB[0]);
        const short8 b1 = *(const short8*)(b + offB[1]);
        acc[0][0] = __builtin_amdgcn_mfma_f32_16x16x32_bf16(a0, b0, acc[0][0], 0, 0, 0);
        acc[0][1] = __builtin_amdgcn_mfma_f32_16x16x32_bf16(a0, b1, acc[0][1], 0, 0, 0);
        acc[1][0] = __builtin_amdgcn_mfma_f32_16x16x32_bf16(a1, b0, acc[1][0], 0, 0, 0);
        acc[1][1] = __builtin_amdgcn_mfma_f32_16x16x32_bf16(a1, b1, acc[1][1], 0, 0, 0);
    }
#pragma unroll
    for (int i = 0; i < 2; ++i) {
        const int mg = m0 + moff + i * 16 + quad * 4;
#pragma unroll
        for (int rr = 0; rr < 4; ++rr)
#pragma unroll
            for (int j = 0; j < 2; ++j) {
                const int ng = n0 + noff + j * 16 + l15;
                Cp[(size_t)(mg + rr) * BATCH + ng] = acc[i][j][rr];
            }
    }
}

// ---------------------------------------------------------------------------
// Fused finish: sum Z partials + bias, per-column (batch) LN stats computed
// locally (block owns 8 columns), LN+ReLU, write bf16 [b][k]. Two passes
// over L2/LLC-hot partials; no global stats, no atomics.
__device__ __forceinline__ void fin_stage(
    u16* SM, int unit, const float* __restrict__ Cz, int M, int Z,
    const float* __restrict__ bias_l, const float* __restrict__ gamma_l,
    const float* __restrict__ beta_l, u16* __restrict__ actb, float invM) {
    float* redS = (float*)SM;            // [32][8]
    float* redQ = redS + 256;            // [32][8]
    float* meanL = redQ + 256;           // [8]
    float* rstdL = meanL + 8;            // [8]
    const int t = threadIdx.x;
    const int c = t & 7;                  // local col 0..7
    const int rl = t >> 3;                // row lane 0..31
    const int cg = (unit << 3) + c;       // global batch column
    const size_t zs = (size_t)M * BATCH;

    float sum = 0.f, sq = 0.f;
    for (int m8 = rl * 8; m8 < M; m8 += 256) {
#pragma unroll
        for (int i = 0; i < 8; ++i) {
            const int m = m8 + i;
            float v = bias_l[m];
            for (int z = 0; z < Z; ++z)
                v += Cz[(size_t)z * zs + (size_t)m * BATCH + cg];
            sum += v; sq += v * v;
        }
    }
    redS[rl * 8 + c] = sum; redQ[rl * 8 + c] = sq;
    __syncthreads();
    if (t < 8) {
        float s = 0.f, qq = 0.f;
        for (int r = 0; r < 32; ++r) { s += redS[r * 8 + t]; qq += redQ[r * 8 + t]; }
        const float mean = s * invM;
        const float var = qq * invM - mean * mean;
        meanL[t] = mean;
        rstdL[t] = rsqrtf(var + EPS);
    }
    __syncthreads();
    const float mean = meanL[c], rstd = rstdL[c];

    for (int m8 = rl * 8; m8 < M; m8 += 256) {
        u16 pk[8];
#pragma unroll
        for (int i = 0; i < 8; ++i) {
            const int m = m8 + i;
            float v = bias_l[m];
            for (int z = 0; z < Z; ++z)
                v += Cz[(size_t)z * zs + (size_t)m * BATCH + cg];
            v = fmaf(gamma_l[m] * (v - mean), rstd, beta_l[m]);
            pk[i] = f2bf(fmaxf(v, 0.0f));
        }
        *(uint4*)(actb + (size_t)cg * M + m8) = *(const uint4*)pk;
    }
}

// ---------------------------------------------------------------------------
// init: zero barrier state (gen + NB flags).
__global__ __launch_bounds__(256) void init(u32* __restrict__ bar) {
    for (int i = threadIdx.x; i < NB + 1; i += 256) bar[i] = 0u;
}

// ---------------------------------------------------------------------------
__global__ __launch_bounds__(256, 4) void mega(
    const float* __restrict__ x, const float* __restrict__ weight,
    const float* __restrict__ bias, const float* __restrict__ ln_gamma,
    const float* __restrict__ ln_beta, const int* __restrict__ edge_src,
    float* __restrict__ out, void* __restrict__ ws) {
    __shared__ uint4 smraw[1024];   // 16 KB, all stages alias this
    u16* SM = (u16*)smraw;

    // ws layout
    float* Cz1   = (float*)ws;                         // 4 x [2048x512]
    float* Cz2   = Cz1 + (size_t)4 * 2048 * 512;       // 8 x [1024x512]
    float* Cz3   = Cz2 + (size_t)8 * 1024 * 512;       // 8 x [512x512]
    u16*   xb    = (u16*)(Cz3 + (size_t)8 * 512 * 512);// [512x4096]
    u16*   actb1 = xb + (size_t)512 * 4096;            // [512x2048]
    u16*   actb2 = actb1 + (size_t)512 * 2048;         // [512x1024]
    u16*   actb3 = actb2 + (size_t)512 * 1024;         // [512x512]
    u16*   Wd    = actb3 + (size_t)512 * 512;          // 11534336 bf16
    u32*   bar   = (u32*)(Wd + 11534336);              // gen, flags[NB]
    u32* gen = bar, *flags = bar + 1;

    const int bid = blockIdx.x, t = threadIdx.x;

    // ---- stage 0: prep (densify W, x->bf16)
    for (int u = bid; u < 4096; u += NB) {
        __syncthreads();   // LDS reuse guard between loop iterations
        if (u < 3584) {
            float* row = (float*)SM;
            int Kin, ebase, srcbase; u16* outrow;
            if (u < 2048)      { Kin = 4096; ebase = u * 128;                 srcbase = 0;    outrow = Wd + (size_t)u * 4096; }
            else if (u < 3072) { int q2 = u - 2048; Kin = 2048; ebase = 262144 + q2 * 128; srcbase = 4096; outrow = Wd + 8388608  + (size_t)q2 * 2048; }
            else               { int q2 = u - 3072; Kin = 1024; ebase = 393216 + q2 * 128; srcbase = 6144; outrow = Wd + 10485760 + (size_t)q2 * 1024; }
            for (int k = t; k < Kin; k += 256) row[k] = 0.f;
            __syncthreads();
            if (t < FAN_IN)
                atomicAdd(&row[edge_src[ebase + t] - srcbase], weight[ebase + t]);
            __syncthreads();
            for (int k0 = t * 8; k0 < Kin; k0 += 2048) {
                u16 pk[8];
#pragma unroll
                for (int i = 0; i < 8; ++i) pk[i] = f2bf(row[k0 + i]);
                *(uint4*)(outrow + k0) = *(const uint4*)pk;
            }
        } else {
            const int b = u - 3584;
            const float* xr = x + (size_t)b * 4096;
            u16* xo = xb + (size_t)b * 4096;
            for (int k0 = t * 8; k0 < 4096; k0 += 2048) {
                const float4 f0 = *(const float4*)(xr + k0);
                const float4 f1 = *(const float4*)(xr + k0 + 4);
                uint4 pk;
                pk.x = f2bf(f0.x) | ((u32)f2bf(f0.y) << 16);
                pk.y = f2bf(f0.z) | ((u32)f2bf(f0.w) << 16);
                pk.z = f2bf(f1.x) | ((u32)f2bf(f1.y) << 16);
                pk.w = f2bf(f1.z) | ((u32)f2bf(f1.w) << 16);
                *(uint4*)(xo + k0) = pk;
            }
        }
    }
    gsync(flags, gen, 1);

    // ---- layer 1: G1 (1024 units: 32m x 8n x 4z, kchunk 1024)
    gemm_stage(SM, bid, 5, Wd, xb, Cz1, 2048, 4096, 1024);
    gsync(flags, gen, 2);
    if (bid < 64) fin_stage(SM, bid, Cz1, 2048, 4, bias, ln_gamma, ln_beta,
                            actb1, 1.0f / 2048.0f);
    gsync(flags, gen, 3);

    // ---- layer 2: G2 (1024 units: 16m x 8n x 8z, kchunk 256)
    gemm_stage(SM, bid, 4, Wd + 8388608, actb1, Cz2, 1024, 2048, 256);
    gsync(flags, gen, 4);
    if (bid < 64) fin_stage(SM, bid, Cz2, 1024, 8, bias + 2048,
                            ln_gamma + 2048, ln_beta + 2048, actb2,
                            1.0f / 1024.0f);
    gsync(flags, gen, 5);

    // ---- layer 3: G3 (512 units: 8m x 8n x 8z, kchunk 128)
    if (bid < 512) gemm_stage(SM, bid, 3, Wd + 10485760, actb2, Cz3, 512, 1024, 128);
    gsync(flags, gen, 6);
    if (bid < 64) fin_stage(SM, bid, Cz3, 512, 8, bias + 3072,
                            ln_gamma + 3072, ln_beta + 3072, actb3,
                            1.0f / 512.0f);
    gsync(flags, gen, 7);

    // ---- output layer: 4 units x 256 outputs
    if (bid < 4) {
        float* w_s = (float*)SM;
        int*   s_s = (int*)(w_s + 256);
        w_s[t] = weight[458752 + t];
        s_s[t] = edge_src[458752 + t] - 7168;
        __syncthreads();
        const int g = bid * 256 + t;        // 0..1023
        const int b = g >> 1, j = g & 1;
        const u16* rowp = actb3 + (size_t)b * 512;
        const int kb = j * FAN_IN;
        float acc = 0.f;
#pragma unroll 8
        for (int k = 0; k < FAN_IN; ++k)
            acc += w_s[kb + k] * bf2f(rowp[s_s[kb + k]]);
        out[(size_t)b * 2 + j] = acc + bias[3584 + j];
    }
}

// ---------------------------------------------------------------------------
extern "C" void kernel_launch(void* const* d_in, const int* in_sizes, int n_in,
                              void* d_out, int out_size, void* d_ws, size_t ws_size,
                              hipStream_t stream) {
    const float* x        = (const float*)d_in[0];
    const float* weight   = (const float*)d_in[1];
    const float* bias     = (const float*)d_in[2];
    const float* ln_gamma = (const float*)d_in[3];
    const float* ln_beta  = (const float*)d_in[4];
    const int*   edge_src = (const int*)d_in[5];
    float* out = (float*)d_out;

    // barrier pointer (same arithmetic as in mega)
    float* Czall = (float*)d_ws;
    u16* xb = (u16*)(Czall + (size_t)4 * 2048 * 512 + (size_t)8 * 1024 * 512 +
                     (size_t)8 * 512 * 512);
    u16* Wd = xb + (size_t)512 * 4096 + (size_t)512 * 2048 +
              (size_t)512 * 1024 + (size_t)512 * 512;
    u32* bar = (u32*)(Wd + 11534336);

    init<<<1, 256, 0, stream>>>(bar);
    mega<<<NB, 256, 0, stream>>>(x, weight, bias, ln_gamma, ln_beta,
                                 edge_src, out, d_ws);
}

// Round 11
// 131.189 us; speedup vs baseline: 9.7306x; 3.3169x over previous
//
#include <hip/hip_runtime.h>

// LAYER_IDX = [0, 4096, 6144, 7168, 7680, 7682]
// layer1: 4096->2048 ebase 0       | layer2: 2048->1024 ebase 262144
// layer3: 1024->512  ebase 393216  | out: 512->2        ebase 458752
#define BATCH 512
#define FAN_IN 128
#define EPS 1e-5f

typedef unsigned short u16;
typedef unsigned int u32;
typedef __attribute__((ext_vector_type(8))) short short8;   // 8 bf16
typedef __attribute__((ext_vector_type(4))) float f32x4;

__device__ __forceinline__ u16 f2bf(float f) {   // fp32->bf16 RNE
    union { float f; u32 u; } v; v.f = f;
    u32 r = v.u + 0x7fffu + ((v.u >> 16) & 1u);
    return (u16)(r >> 16);
}
__device__ __forceinline__ void ld16(const void* g, void* l) {  // async global->LDS 16B
    __builtin_amdgcn_global_load_lds(
        (const __attribute__((address_space(1))) u32*)g,
        (__attribute__((address_space(3))) u32*)l, 16, 0, 0);
}

// ---------------------------------------------------------------------------
// prep: densify W (bf16 [m][k]) + convert x -> bf16 (same layout, no transpose).
__global__ __launch_bounds__(256) void prep(
    const float* __restrict__ weight, const int* __restrict__ edge_src,
    const float* __restrict__ x, u16* __restrict__ Wd, u16* __restrict__ xb) {
    __shared__ float row[4096];
    const int bid = blockIdx.x, t = threadIdx.x;
    if (bid < 3584) {  // densify one target node (dup edges accumulate)
        int Kin, ebase, srcbase; u16* outrow;
        if (bid < 2048)      { Kin = 4096; ebase = bid * 128;                 srcbase = 0;    outrow = Wd + (size_t)bid * 4096; }
        else if (bid < 3072) { int q = bid - 2048; Kin = 2048; ebase = 262144 + q * 128; srcbase = 4096; outrow = Wd + 8388608  + (size_t)q * 2048; }
        else                 { int q = bid - 3072; Kin = 1024; ebase = 393216 + q * 128; srcbase = 6144; outrow = Wd + 10485760 + (size_t)q * 1024; }
        for (int k = t; k < Kin; k += 256) row[k] = 0.f;
        __syncthreads();
        if (t < FAN_IN)
            atomicAdd(&row[edge_src[ebase + t] - srcbase], weight[ebase + t]);
        __syncthreads();
        for (int k0 = t * 8; k0 < Kin; k0 += 2048) {
            u16 pk[8];
#pragma unroll
            for (int i = 0; i < 8; ++i) pk[i] = f2bf(row[k0 + i]);
            *(uint4*)(outrow + k0) = *(const uint4*)pk;
        }
    } else {  // x row -> bf16 (batch-major kept)
        const int b = bid - 3584;
        const float* xr = x + (size_t)b * 4096;
        u16* xo = xb + (size_t)b * 4096;
        for (int k0 = t * 8; k0 < 4096; k0 += 2048) {
            const float4 f0 = *(const float4*)(xr + k0);
            const float4 f1 = *(const float4*)(xr + k0 + 4);
            uint4 pk;
            pk.x = f2bf(f0.x) | ((u32)f2bf(f0.y) << 16);
            pk.y = f2bf(f0.z) | ((u32)f2bf(f0.w) << 16);
            pk.z = f2bf(f1.x) | ((u32)f2bf(f1.y) << 16);
            pk.w = f2bf(f1.z) | ((u32)f2bf(f1.w) << 16);
            *(uint4*)(xo + k0) = pk;
        }
    }
}

// ---------------------------------------------------------------------------
// Partial GEMM, batch-major output: Cz[z][n=batch][m=node] for K-chunk z.
// A = Act [512 x K] (batch rows), B = W [M x K] (node rows), both bf16
// k-contiguous. 64x64 tile, BK=32, dbuf LDS via global_load_lds, XOR swizzle.
// grid (M/64, 8, Z). Plain stores (no init needed).
__global__ __launch_bounds__(256, 8) void gemm_bt(
    const u16* __restrict__ Act, const u16* __restrict__ W,
    float* __restrict__ Cz, int M, int K, int kchunk) {
    __shared__ u16 sA[2][2048];   // batch tile [row*32 + chunk*8] swizzled
    __shared__ u16 sB[2][2048];   // node tile
    const int tid = threadIdx.x;
    const int m0 = blockIdx.x * 64;           // node tile (B operand)
    const int n0 = blockIdx.y * 64;           // batch tile (A operand)
    const int kbase = blockIdx.z * kchunk;
    float* Cp = Cz + (size_t)blockIdx.z * BATCH * M;

    const int r = tid >> 2, c = tid & 3;
    const int q = c ^ ((r ^ (r >> 2)) & 3);
    const u16* gA = Act + (size_t)(n0 + r) * K + kbase + q * 8;
    const u16* gB = W + (size_t)(m0 + r) * K + kbase + q * 8;
    const int lo = tid * 8;

    const int wave = tid >> 6, lane = tid & 63;
    const int l15 = lane & 15, quad = lane >> 4;
    const int aoff = (wave & 1) * 32, boff = (wave >> 1) * 32;
    int offA[2], offB[2];
#pragma unroll
    for (int i = 0; i < 2; ++i) {
        const int ra = aoff + i * 16 + l15;
        offA[i] = ra * 32 + ((quad ^ ((ra ^ (ra >> 2)) & 3)) * 8);
        const int rb = boff + i * 16 + l15;
        offB[i] = rb * 32 + ((quad ^ ((rb ^ (rb >> 2)) & 3)) * 8);
    }

    f32x4 acc[2][2] = {};
    const int niter = kchunk >> 5;
    ld16(gA, &sA[0][lo]); ld16(gB, &sB[0][lo]);
    for (int it = 0; it < niter; ++it) {
        __syncthreads();
        if (it + 1 < niter) {
            const int k0 = (it + 1) << 5;
            const int nb = (it + 1) & 1;
            ld16(gA + k0, &sA[nb][lo]); ld16(gB + k0, &sB[nb][lo]);
        }
        const u16* a = sA[it & 1];
        const u16* b = sB[it & 1];
        const short8 a0 = *(const short8*)(a + offA[0]);
        const short8 a1 = *(const short8*)(a + offA[1]);
        const short8 b0 = *(const short8*)(b + offB[0]);
        const short8 b1 = *(const short8*)(b + offB[1]);
        acc[0][0] = __builtin_amdgcn_mfma_f32_16x16x32_bf16(a0, b0, acc[0][0], 0, 0, 0);
        acc[0][1] = __builtin_amdgcn_mfma_f32_16x16x32_bf16(a0, b1, acc[0][1], 0, 0, 0);
        acc[1][0] = __builtin_amdgcn_mfma_f32_16x16x32_bf16(a1, b0, acc[1][0], 0, 0, 0);
        acc[1][1] = __builtin_amdgcn_mfma_f32_16x16x32_bf16(a1, b1, acc[1][1], 0, 0, 0);
    }
    // epilogue: D row (quad*4+rr) = batch, col (l15) = node -> coalesced
#pragma unroll
    for (int i = 0; i < 2; ++i) {
        const int nb = n0 + aoff + i * 16 + quad * 4;
#pragma unroll
        for (int rr = 0; rr < 4; ++rr)
#pragma unroll
            for (int j = 0; j < 2; ++j) {
                const int mg = m0 + boff + j * 16 + l15;
                Cp[(size_t)(nb + rr) * M + mg] = acc[i][j][rr];
            }
    }
}

// ---------------------------------------------------------------------------
// fin: one block per batch row n. Sum Z partials + bias, row mean/var (biased),
// LN+ReLU, write bf16 actb[n][m] (next GEMM's A operand). If WOUT: keep the
// post-LN row in LDS and emit the 2-node sparse output layer instead.
template <int M, int Z, bool WOUT>
__global__ __launch_bounds__(256) void fin(
    const float* __restrict__ Cz, const float* __restrict__ bias_l,
    const float* __restrict__ gamma_l, const float* __restrict__ beta_l,
    u16* __restrict__ actb, const float* __restrict__ weight,
    const int* __restrict__ edge_src, const float* __restrict__ obias,
    float* __restrict__ out) {
    __shared__ float red[8];
    __shared__ float mrs[2];
    __shared__ float rowL[512];
    __shared__ float w_s[256];
    __shared__ int   s_s[256];
    __shared__ float pr[256];

    const int n = blockIdx.x, t = threadIdx.x;
    const size_t zs = (size_t)BATCH * M;
    const float* base = Cz + (size_t)n * M;

    if (WOUT) { w_s[t] = weight[458752 + t]; s_s[t] = edge_src[458752 + t] - 7168; }

    float sum = 0.f, sq = 0.f;
    for (int m = t * 4; m < M; m += 1024) {
        float4 v = *(const float4*)(bias_l + m);
#pragma unroll
        for (int z = 0; z < Z; ++z) {
            const float4 cv = *(const float4*)(base + (size_t)z * zs + m);
            v.x += cv.x; v.y += cv.y; v.z += cv.z; v.w += cv.w;
        }
        sum += v.x + v.y + v.z + v.w;
        sq += v.x * v.x + v.y * v.y + v.z * v.z + v.w * v.w;
    }
#pragma unroll
    for (int o = 32; o; o >>= 1) {
        sum += __shfl_down(sum, o);
        sq += __shfl_down(sq, o);
    }
    if ((t & 63) == 0) { red[(t >> 6) * 2] = sum; red[(t >> 6) * 2 + 1] = sq; }
    __syncthreads();
    if (t == 0) {
        const float s = red[0] + red[2] + red[4] + red[6];
        const float qq = red[1] + red[3] + red[5] + red[7];
        const float mean = s / (float)M;
        const float var = qq / (float)M - mean * mean;
        mrs[0] = mean; mrs[1] = rsqrtf(var + EPS);
    }
    __syncthreads();
    const float mean = mrs[0], rstd = mrs[1];

    for (int m = t * 4; m < M; m += 1024) {
        float4 v = *(const float4*)(bias_l + m);
#pragma unroll
        for (int z = 0; z < Z; ++z) {
            const float4 cv = *(const float4*)(base + (size_t)z * zs + m);
            v.x += cv.x; v.y += cv.y; v.z += cv.z; v.w += cv.w;
        }
        const float4 g = *(const float4*)(gamma_l + m);
        const float4 bt = *(const float4*)(beta_l + m);
        float o0 = fmaxf(fmaf(g.x * (v.x - mean), rstd, bt.x), 0.f);
        float o1 = fmaxf(fmaf(g.y * (v.y - mean), rstd, bt.y), 0.f);
        float o2 = fmaxf(fmaf(g.z * (v.z - mean), rstd, bt.z), 0.f);
        float o3 = fmaxf(fmaf(g.w * (v.w - mean), rstd, bt.w), 0.f);
        if (WOUT) {
            rowL[m + 0] = o0; rowL[m + 1] = o1; rowL[m + 2] = o2; rowL[m + 3] = o3;
        } else {
            u16 pk[4] = {f2bf(o0), f2bf(o1), f2bf(o2), f2bf(o3)};
            *(uint2*)(actb + (size_t)n * M + m) = *(const uint2*)pk;
        }
    }
    if (WOUT) {   // sparse output layer from the post-LN row in LDS
        __syncthreads();
        pr[t] = w_s[t] * rowL[s_s[t]];
        __syncthreads();
        if (t < 2) {
            float s = 0.f;
            for (int k = 0; k < FAN_IN; ++k) s += pr[t * FAN_IN + k];
            out[(size_t)n * 2 + t] = s + obias[t];
        }
    }
}

// ---------------------------------------------------------------------------
extern "C" void kernel_launch(void* const* d_in, const int* in_sizes, int n_in,
                              void* d_out, int out_size, void* d_ws, size_t ws_size,
                              hipStream_t stream) {
    const float* x        = (const float*)d_in[0];
    const float* weight   = (const float*)d_in[1];
    const float* bias     = (const float*)d_in[2];
    const float* ln_gamma = (const float*)d_in[3];
    const float* ln_beta  = (const float*)d_in[4];
    const int*   edge_src = (const int*)d_in[5];
    float* out = (float*)d_out;

    // ws layout: all Cz batch-major [z][512][M]
    float* Cz1 = (float*)d_ws;                         // 4 x [512x2048]
    float* Cz2 = Cz1 + (size_t)4 * 512 * 2048;         // 8 x [512x1024]
    float* Cz3 = Cz2 + (size_t)8 * 512 * 1024;         // 8 x [512x512]
    u16* xb    = (u16*)(Cz3 + (size_t)8 * 512 * 512);  // [512x4096] bf16
    u16* actb1 = xb + (size_t)512 * 4096;              // [512x2048]
    u16* actb2 = actb1 + (size_t)512 * 2048;           // [512x1024]
    u16* Wd    = actb2 + (size_t)512 * 1024;           // 11534336 bf16

    // 1) prep
    prep<<<4096, 256, 0, stream>>>(weight, edge_src, x, Wd, xb);
    // 2) G1: C1[n][m] = xb[512x4096] x W1[2048x4096]^T, Z=4 (1024 blocks)
    gemm_bt<<<dim3(32, 8, 4), 256, 0, stream>>>(xb, Wd, Cz1, 2048, 4096, 1024);
    // 3) fin1 -> actb1 (bf16 batch-major)
    fin<2048, 4, false><<<512, 256, 0, stream>>>(
        Cz1, bias, ln_gamma, ln_beta, actb1, nullptr, nullptr, nullptr, nullptr);
    // 4) G2: Z=8 (1024 blocks)
    gemm_bt<<<dim3(16, 8, 8), 256, 0, stream>>>(actb1, Wd + 8388608, Cz2, 1024, 2048, 256);
    // 5) fin2 -> actb2
    fin<1024, 8, false><<<512, 256, 0, stream>>>(
        Cz2, bias + 2048, ln_gamma + 2048, ln_beta + 2048, actb2,
        nullptr, nullptr, nullptr, nullptr);
    // 6) G3: Z=8 (512 blocks)
    gemm_bt<<<dim3(8, 8, 8), 256, 0, stream>>>(actb2, Wd + 10485760, Cz3, 512, 1024, 128);
    // 7) fin3 + sparse output layer -> d_out [512, 2]
    fin<512, 8, true><<<512, 256, 0, stream>>>(
        Cz3, bias + 3072, ln_gamma + 3072, ln_beta + 3072, nullptr,
        weight, edge_src, bias + 3584, out);
}

// Round 12
// 128.386 us; speedup vs baseline: 9.9430x; 1.0218x over previous
//
#include <hip/hip_runtime.h>

// LAYER_IDX = [0, 4096, 6144, 7168, 7680, 7682]
// layer1: 4096->2048 ebase 0       | layer2: 2048->1024 ebase 262144
// layer3: 1024->512  ebase 393216  | out: 512->2        ebase 458752
#define BATCH 512
#define FAN_IN 128
#define EPS 1e-5f

typedef unsigned short u16;
typedef unsigned int u32;
typedef __attribute__((ext_vector_type(8))) short short8;   // 8 bf16
typedef __attribute__((ext_vector_type(4))) float f32x4;

__device__ __forceinline__ u16 f2bf(float f) {   // fp32->bf16 RNE
    union { float f; u32 u; } v; v.f = f;
    u32 r = v.u + 0x7fffu + ((v.u >> 16) & 1u);
    return (u16)(r >> 16);
}
__device__ __forceinline__ void ld16(const void* g, void* l) {  // async global->LDS 16B
    __builtin_amdgcn_global_load_lds(
        (const __attribute__((address_space(1))) u32*)g,
        (__attribute__((address_space(3))) u32*)l, 16, 0, 0);
}

// ---------------------------------------------------------------------------
// prep: densify W (bf16 [m][k]) + convert x -> bf16 (same layout, no transpose).
__global__ __launch_bounds__(256) void prep(
    const float* __restrict__ weight, const int* __restrict__ edge_src,
    const float* __restrict__ x, u16* __restrict__ Wd, u16* __restrict__ xb) {
    __shared__ float row[4096];
    const int bid = blockIdx.x, t = threadIdx.x;
    if (bid < 3584) {  // densify one target node (dup edges accumulate)
        int Kin, ebase, srcbase; u16* outrow;
        if (bid < 2048)      { Kin = 4096; ebase = bid * 128;                 srcbase = 0;    outrow = Wd + (size_t)bid * 4096; }
        else if (bid < 3072) { int q = bid - 2048; Kin = 2048; ebase = 262144 + q * 128; srcbase = 4096; outrow = Wd + 8388608  + (size_t)q * 2048; }
        else                 { int q = bid - 3072; Kin = 1024; ebase = 393216 + q * 128; srcbase = 6144; outrow = Wd + 10485760 + (size_t)q * 1024; }
        for (int k = t; k < Kin; k += 256) row[k] = 0.f;
        __syncthreads();
        if (t < FAN_IN)
            atomicAdd(&row[edge_src[ebase + t] - srcbase], weight[ebase + t]);
        __syncthreads();
        for (int k0 = t * 8; k0 < Kin; k0 += 2048) {
            u16 pk[8];
#pragma unroll
            for (int i = 0; i < 8; ++i) pk[i] = f2bf(row[k0 + i]);
            *(uint4*)(outrow + k0) = *(const uint4*)pk;
        }
    } else {  // x row -> bf16 (batch-major kept)
        const int b = bid - 3584;
        const float* xr = x + (size_t)b * 4096;
        u16* xo = xb + (size_t)b * 4096;
        for (int k0 = t * 8; k0 < 4096; k0 += 2048) {
            const float4 f0 = *(const float4*)(xr + k0);
            const float4 f1 = *(const float4*)(xr + k0 + 4);
            uint4 pk;
            pk.x = f2bf(f0.x) | ((u32)f2bf(f0.y) << 16);
            pk.y = f2bf(f0.z) | ((u32)f2bf(f0.w) << 16);
            pk.z = f2bf(f1.x) | ((u32)f2bf(f1.y) << 16);
            pk.w = f2bf(f1.z) | ((u32)f2bf(f1.w) << 16);
            *(uint4*)(xo + k0) = pk;
        }
    }
}

// ---------------------------------------------------------------------------
// Partial GEMM, batch-major output: Cz[z][n=batch][m=node] for K-chunk z.
// A = Act [512 x K] (batch rows), B = W [M x K] (node rows), both bf16
// k-contiguous. 64x64 tile, BK=32, dbuf LDS via global_load_lds, XOR swizzle.
// grid (M/64, 8, Z). Plain stores (no init needed).
__global__ __launch_bounds__(256, 8) void gemm_bt(
    const u16* __restrict__ Act, const u16* __restrict__ W,
    float* __restrict__ Cz, int M, int K, int kchunk) {
    __shared__ u16 sA[2][2048];   // batch tile [row*32 + chunk*8] swizzled
    __shared__ u16 sB[2][2048];   // node tile
    const int tid = threadIdx.x;
    const int m0 = blockIdx.x * 64;           // node tile (B operand)
    const int n0 = blockIdx.y * 64;           // batch tile (A operand)
    const int kbase = blockIdx.z * kchunk;
    float* Cp = Cz + (size_t)blockIdx.z * BATCH * M;

    const int r = tid >> 2, c = tid & 3;
    const int q = c ^ ((r ^ (r >> 2)) & 3);
    const u16* gA = Act + (size_t)(n0 + r) * K + kbase + q * 8;
    const u16* gB = W + (size_t)(m0 + r) * K + kbase + q * 8;
    const int lo = tid * 8;

    const int wave = tid >> 6, lane = tid & 63;
    const int l15 = lane & 15, quad = lane >> 4;
    const int aoff = (wave & 1) * 32, boff = (wave >> 1) * 32;
    int offA[2], offB[2];
#pragma unroll
    for (int i = 0; i < 2; ++i) {
        const int ra = aoff + i * 16 + l15;
        offA[i] = ra * 32 + ((quad ^ ((ra ^ (ra >> 2)) & 3)) * 8);
        const int rb = boff + i * 16 + l15;
        offB[i] = rb * 32 + ((quad ^ ((rb ^ (rb >> 2)) & 3)) * 8);
    }

    f32x4 acc[2][2] = {};
    const int niter = kchunk >> 5;
    ld16(gA, &sA[0][lo]); ld16(gB, &sB[0][lo]);
    for (int it = 0; it < niter; ++it) {
        __syncthreads();
        if (it + 1 < niter) {
            const int k0 = (it + 1) << 5;
            const int nb = (it + 1) & 1;
            ld16(gA + k0, &sA[nb][lo]); ld16(gB + k0, &sB[nb][lo]);
        }
        const u16* a = sA[it & 1];
        const u16* b = sB[it & 1];
        const short8 a0 = *(const short8*)(a + offA[0]);
        const short8 a1 = *(const short8*)(a + offA[1]);
        const short8 b0 = *(const short8*)(b + offB[0]);
        const short8 b1 = *(const short8*)(b + offB[1]);
        acc[0][0] = __builtin_amdgcn_mfma_f32_16x16x32_bf16(a0, b0, acc[0][0], 0, 0, 0);
        acc[0][1] = __builtin_amdgcn_mfma_f32_16x16x32_bf16(a0, b1, acc[0][1], 0, 0, 0);
        acc[1][0] = __builtin_amdgcn_mfma_f32_16x16x32_bf16(a1, b0, acc[1][0], 0, 0, 0);
        acc[1][1] = __builtin_amdgcn_mfma_f32_16x16x32_bf16(a1, b1, acc[1][1], 0, 0, 0);
    }
    // epilogue: D row (quad*4+rr) = batch, col (l15) = node -> coalesced
#pragma unroll
    for (int i = 0; i < 2; ++i) {
        const int nb = n0 + aoff + i * 16 + quad * 4;
#pragma unroll
        for (int rr = 0; rr < 4; ++rr)
#pragma unroll
            for (int j = 0; j < 2; ++j) {
                const int mg = m0 + boff + j * 16 + l15;
                Cp[(size_t)(nb + rr) * M + mg] = acc[i][j][rr];
            }
    }
}

// ---------------------------------------------------------------------------
// fin: one block per batch row n. Single global pass: sum Z partials + bias
// into an LDS row cache, row mean/var from shuffle reduce, then LN+ReLU from
// LDS (no second global read), write bf16 actb[n][m]. If WOUT: normalize in
// LDS and emit the 2-node sparse output layer.
template <int M, int Z, bool WOUT>
__global__ __launch_bounds__(256) void fin(
    const float* __restrict__ Cz, const float* __restrict__ bias_l,
    const float* __restrict__ gamma_l, const float* __restrict__ beta_l,
    u16* __restrict__ actb, const float* __restrict__ weight,
    const int* __restrict__ edge_src, const float* __restrict__ obias,
    float* __restrict__ out) {
    __shared__ float rowL[M];            // summed pre-LN row (<= 8 KB)
    __shared__ float red[8];
    __shared__ float mrs[2];
    __shared__ float w_s[256];
    __shared__ int   s_s[256];
    __shared__ float pr[256];

    const int n = blockIdx.x, t = threadIdx.x;
    const size_t zs = (size_t)BATCH * M;
    const float* base = Cz + (size_t)n * M;

    if (WOUT) { w_s[t] = weight[458752 + t]; s_s[t] = edge_src[458752 + t] - 7168; }

    // pass 1 (global): sum partials + bias -> LDS row; accumulate stats
    float sum = 0.f, sq = 0.f;
    for (int m = t * 4; m < M; m += 1024) {
        float4 v = *(const float4*)(bias_l + m);
#pragma unroll
        for (int z = 0; z < Z; ++z) {
            const float4 cv = *(const float4*)(base + (size_t)z * zs + m);
            v.x += cv.x; v.y += cv.y; v.z += cv.z; v.w += cv.w;
        }
        *(float4*)(rowL + m) = v;
        sum += v.x + v.y + v.z + v.w;
        sq += v.x * v.x + v.y * v.y + v.z * v.z + v.w * v.w;
    }
#pragma unroll
    for (int o = 32; o; o >>= 1) {
        sum += __shfl_down(sum, o);
        sq += __shfl_down(sq, o);
    }
    if ((t & 63) == 0) { red[(t >> 6) * 2] = sum; red[(t >> 6) * 2 + 1] = sq; }
    __syncthreads();
    if (t == 0) {
        const float s = red[0] + red[2] + red[4] + red[6];
        const float qq = red[1] + red[3] + red[5] + red[7];
        const float mean = s / (float)M;
        const float var = qq / (float)M - mean * mean;
        mrs[0] = mean; mrs[1] = rsqrtf(var + EPS);
    }
    __syncthreads();
    const float mean = mrs[0], rstd = mrs[1];

    // pass 2 (LDS only): LN + ReLU
    for (int m = t * 4; m < M; m += 1024) {
        const float4 v = *(const float4*)(rowL + m);
        const float4 g = *(const float4*)(gamma_l + m);
        const float4 bt = *(const float4*)(beta_l + m);
        const float o0 = fmaxf(fmaf(g.x * (v.x - mean), rstd, bt.x), 0.f);
        const float o1 = fmaxf(fmaf(g.y * (v.y - mean), rstd, bt.y), 0.f);
        const float o2 = fmaxf(fmaf(g.z * (v.z - mean), rstd, bt.z), 0.f);
        const float o3 = fmaxf(fmaf(g.w * (v.w - mean), rstd, bt.w), 0.f);
        if (WOUT) {
            rowL[m + 0] = o0; rowL[m + 1] = o1; rowL[m + 2] = o2; rowL[m + 3] = o3;
        } else {
            u16 pk[4] = {f2bf(o0), f2bf(o1), f2bf(o2), f2bf(o3)};
            *(uint2*)(actb + (size_t)n * M + m) = *(const uint2*)pk;
        }
    }
    if (WOUT) {   // sparse output layer from the post-LN row in LDS
        __syncthreads();
        pr[t] = w_s[t] * rowL[s_s[t]];
        __syncthreads();
        if (t < 2) {
            float s = 0.f;
            for (int k = 0; k < FAN_IN; ++k) s += pr[t * FAN_IN + k];
            out[(size_t)n * 2 + t] = s + obias[t];
        }
    }
}

// ---------------------------------------------------------------------------
extern "C" void kernel_launch(void* const* d_in, const int* in_sizes, int n_in,
                              void* d_out, int out_size, void* d_ws, size_t ws_size,
                              hipStream_t stream) {
    const float* x        = (const float*)d_in[0];
    const float* weight   = (const float*)d_in[1];
    const float* bias     = (const float*)d_in[2];
    const float* ln_gamma = (const float*)d_in[3];
    const float* ln_beta  = (const float*)d_in[4];
    const int*   edge_src = (const int*)d_in[5];
    float* out = (float*)d_out;

    // ws layout: all Cz batch-major [z][512][M]
    float* Cz1 = (float*)d_ws;                         // 4 x [512x2048]
    float* Cz2 = Cz1 + (size_t)4 * 512 * 2048;         // 4 x [512x1024]
    float* Cz3 = Cz2 + (size_t)4 * 512 * 1024;         // 8 x [512x512]
    u16* xb    = (u16*)(Cz3 + (size_t)8 * 512 * 512);  // [512x4096] bf16
    u16* actb1 = xb + (size_t)512 * 4096;              // [512x2048]
    u16* actb2 = actb1 + (size_t)512 * 2048;           // [512x1024]
    u16* Wd    = actb2 + (size_t)512 * 1024;           // 11534336 bf16

    // 1) prep
    prep<<<4096, 256, 0, stream>>>(weight, edge_src, x, Wd, xb);
    // 2) G1: C1[n][m] = xb[512x4096] x W1[2048x4096]^T, Z=4 (1024 blocks)
    gemm_bt<<<dim3(32, 8, 4), 256, 0, stream>>>(xb, Wd, Cz1, 2048, 4096, 1024);
    // 3) fin1 -> actb1 (bf16 batch-major)
    fin<2048, 4, false><<<512, 256, 0, stream>>>(
        Cz1, bias, ln_gamma, ln_beta, actb1, nullptr, nullptr, nullptr, nullptr);
    // 4) G2: Z=4 (512 blocks, 2/CU)
    gemm_bt<<<dim3(16, 8, 4), 256, 0, stream>>>(actb1, Wd + 8388608, Cz2, 1024, 2048, 512);
    // 5) fin2 -> actb2
    fin<1024, 4, false><<<512, 256, 0, stream>>>(
        Cz2, bias + 2048, ln_gamma + 2048, ln_beta + 2048, actb2,
        nullptr, nullptr, nullptr, nullptr);
    // 6) G3: Z=8 (512 blocks)
    gemm_bt<<<dim3(8, 8, 8), 256, 0, stream>>>(actb2, Wd + 10485760, Cz3, 512, 1024, 128);
    // 7) fin3 + sparse output layer -> d_out [512, 2]
    fin<512, 8, true><<<512, 256, 0, stream>>>(
        Cz3, bias + 3072, ln_gamma + 3072, ln_beta + 3072, nullptr,
        weight, edge_src, bias + 3584, out);
}